// Round 10
// baseline (203.561 us; speedup 1.0000x reference)
//
#include <hip/hip_runtime.h>

// YOLO-v1 loss forward, S=7, B=2, C=20, bs=16384.
// R10: mixed cache-policy probe.
//   R9 (all-nt) broke the 2.55 TB/s allocating-load wall -> ~56 us kernel,
//   3.37 TB/s HBM-direct reads. Theory: nt-bypass path and L2/L3-allocating
//   path are SEPARATE walls that can flow in parallel. This round: preds stay
//   non-temporal, labels go back to regular (allocating) loads -> labels'
//   L3-resident half (warmed by the harness restore) is served by L3 while
//   preds stream HBM-direct. Everything else identical to R9.

#define SS 7
#define CELL_STRIDE 30                       // 5*B + C floats per cell
#define WAVE_FLOATS (64 * CELL_STRIDE)       // 1920 floats = 7680 B
#define WAVES_PER_BLOCK 2
#define SLAB_CELLS (64 * WAVES_PER_BLOCK)    // 128
#define NBLOCKS 2560                         // 10 blocks/CU at 15.4 KB LDS

__device__ __forceinline__ void wave_lds_fence() {
    __builtin_amdgcn_fence(__ATOMIC_SEQ_CST, "wavefront");
    __builtin_amdgcn_wave_barrier();
}

// non-temporal 8-byte load, bit-cast to float2 (no FP ops on the double)
__device__ __forceinline__ float2 nt_load_f2(const double* p) {
    const double d = __builtin_nontemporal_load(p);
    union { double d; float2 f; } u;
    u.d = d;
    return u.f;
}

__device__ __forceinline__ float yolo_cell_loss(const float* pv, const float* lv, int cell) {
    const int rem = cell % (SS * SS);
    const float gx = (float)(rem % SS);   // meshgrid 'xy': x = col
    const float gy = (float)(rem / SS);   // y = row

    const float obj = lv[4];
    const float lx = lv[0], ly = lv[1], lw = lv[2], lh = lv[3];
    const float l_cx = (gx + lx) / 7.0f;
    const float l_cy = (gy + ly) / 7.0f;
    const float l_minx = l_cx - lw * 0.5f, l_maxx = l_cx + lw * 0.5f;
    const float l_miny = l_cy - lh * 0.5f, l_maxy = l_cy + lh * 0.5f;
    const float area_l = lw * lh;

    float iou[2], box_err[2], conf[2];
    #pragma unroll
    for (int b = 0; b < 2; ++b) {
        const float px = pv[5 * b + 0], py = pv[5 * b + 1];
        const float pw = pv[5 * b + 2], ph = pv[5 * b + 3];
        conf[b] = pv[5 * b + 4];
        const float p_cx = (gx + px) / 7.0f;
        const float p_cy = (gy + py) / 7.0f;
        const float p_minx = p_cx - pw * 0.5f, p_maxx = p_cx + pw * 0.5f;
        const float p_miny = p_cy - ph * 0.5f, p_maxy = p_cy + ph * 0.5f;
        float iw = fminf(p_maxx, l_maxx) - fmaxf(p_minx, l_minx);
        float ih = fminf(p_maxy, l_maxy) - fmaxf(p_miny, l_miny);
        iw = fmaxf(iw, 0.0f); ih = fmaxf(ih, 0.0f);
        const float inter = iw * ih;
        const float uni = pw * ph + area_l - inter + 1e-10f;
        iou[b] = inter / uni;
        const float dx = px - lx, dy = py - ly;
        const float dw = sqrtf(pw) - sqrtf(lw);
        const float dh = sqrtf(ph) - sqrtf(lh);
        box_err[b] = (dx * dx + dy * dy) + (dw * dw + dh * dh);
    }

    // argmax tie-break: first max wins -> box 1 only if strictly greater
    const int r = (iou[1] > iou[0]) ? 1 : 0;
    const float cr = conf[r], cn = conf[1 - r];

    float loss = obj * (5.0f * box_err[r] + (cr - iou[r]) * (cr - iou[r]));
    loss += 0.5f * ((1.0f - obj) * cr * cr + cn * cn);

    float cls = 0.0f;
    #pragma unroll
    for (int k = 10; k < 30; ++k) {
        const float d = pv[k] - lv[k];
        cls += d * d;
    }
    loss += obj * cls;
    return loss;
}

__global__ __launch_bounds__(128) void yolo_loss_partial(
    const float* __restrict__ preds,
    const float* __restrict__ labels,
    float* __restrict__ partial,
    int nslabs, float inv_bs, int use_atomic)
{
    __shared__ float sh[WAVES_PER_BLOCK * WAVE_FLOATS];   // 15360 B
    const int tid  = threadIdx.x;
    const int lane = tid & 63;
    const int wid  = tid >> 6;
    float*  wsh  = sh + wid * WAVE_FLOATS;   // this wave's private segment
    float2* wsh2 = reinterpret_cast<float2*>(wsh);

    float acc = 0.0f;

    for (int slab = blockIdx.x; slab < nslabs; slab += NBLOCKS) {
        const int cell0 = slab * SLAB_CELLS + wid * 64;
        const double* gp = reinterpret_cast<const double*>(preds  + (size_t)cell0 * CELL_STRIDE);
        const float2* gl = reinterpret_cast<const float2*>(labels + (size_t)cell0 * CELL_STRIDE);

        // ---- issue ALL 30 loads up front: preds NT (HBM-direct stream),
        //      labels REGULAR (L2/L3-allocating path) -> parallel walls ----
        float2 t[15], u[15];
        #pragma unroll
        for (int k = 0; k < 15; ++k) t[k] = nt_load_f2(gp + lane + 64 * k);
        #pragma unroll
        for (int k = 0; k < 15; ++k) u[k] = gl[lane + 64 * k];

        // ---- preds: LDS transpose (wave-private, no HW barrier) ----
        #pragma unroll
        for (int k = 0; k < 15; ++k) wsh2[lane + 64 * k] = t[k];
        wave_lds_fence();   // writes before cross-lane reads
        float pv[CELL_STRIDE];
        {
            const float2* my = reinterpret_cast<const float2*>(wsh + lane * CELL_STRIDE);
            #pragma unroll
            for (int k = 0; k < 15; ++k) { float2 v = my[k]; pv[2*k] = v.x; pv[2*k+1] = v.y; }
        }
        wave_lds_fence();   // reads done before overwrite

        // ---- labels: same segment ----
        #pragma unroll
        for (int k = 0; k < 15; ++k) wsh2[lane + 64 * k] = u[k];
        wave_lds_fence();
        float lv[CELL_STRIDE];
        {
            const float2* my = reinterpret_cast<const float2*>(wsh + lane * CELL_STRIDE);
            #pragma unroll
            for (int k = 0; k < 3; ++k)  { float2 v = my[k]; lv[2*k] = v.x; lv[2*k+1] = v.y; }
            #pragma unroll
            for (int k = 5; k < 15; ++k) { float2 v = my[k]; lv[2*k] = v.x; lv[2*k+1] = v.y; }
        }
        wave_lds_fence();   // reads done before next slab

        acc += yolo_cell_loss(pv, lv, cell0 + lane);
    }

    acc *= inv_bs;

    // wave (64-lane) shuffle reduction
    #pragma unroll
    for (int off = 32; off > 0; off >>= 1)
        acc += __shfl_down(acc, off, 64);

    __shared__ float wsum[WAVES_PER_BLOCK];
    if (lane == 0) wsum[wid] = acc;
    __syncthreads();
    if (tid == 0) {
        const float blocksum = wsum[0] + wsum[1];
        if (use_atomic) atomicAdd(partial, blocksum);        // fallback: partial==out
        else            partial[blockIdx.x] = blocksum;
    }
}

__global__ __launch_bounds__(256) void yolo_reduce(
    const float* __restrict__ partial, float* __restrict__ out, int n)
{
    float acc = 0.0f;
    for (int i = threadIdx.x; i < n; i += 256) acc += partial[i];
    #pragma unroll
    for (int off = 32; off > 0; off >>= 1)
        acc += __shfl_down(acc, off, 64);
    __shared__ float wsum[4];
    const int lane = threadIdx.x & 63;
    const int wid  = threadIdx.x >> 6;
    if (lane == 0) wsum[wid] = acc;
    __syncthreads();
    if (threadIdx.x == 0) out[0] = wsum[0] + wsum[1] + wsum[2] + wsum[3];
}

__global__ void yolo_zero_out(float* out) {
    if (threadIdx.x == 0) out[0] = 0.0f;
}

extern "C" void kernel_launch(void* const* d_in, const int* in_sizes, int n_in,
                              void* d_out, int out_size, void* d_ws, size_t ws_size,
                              hipStream_t stream) {
    const float* preds  = (const float*)d_in[0];
    const float* labels = (const float*)d_in[1];
    float* out = (float*)d_out;

    const int ncells = in_sizes[0] / CELL_STRIDE;        // 802816 (divisible by 128)
    const int nslabs = ncells / SLAB_CELLS;              // 6272
    const int bs     = ncells / (SS * SS);               // 16384
    const float inv_bs = 1.0f / (float)bs;

    if (ws_size >= NBLOCKS * sizeof(float)) {
        float* partial = (float*)d_ws;
        yolo_loss_partial<<<NBLOCKS, 128, 0, stream>>>(preds, labels, partial,
                                                       nslabs, inv_bs, 0);
        yolo_reduce<<<1, 256, 0, stream>>>(partial, out, NBLOCKS);
    } else {
        yolo_zero_out<<<1, 64, 0, stream>>>(out);
        yolo_loss_partial<<<NBLOCKS, 128, 0, stream>>>(preds, labels, out,
                                                       nslabs, inv_bs, 1);
    }
}

// Round 12
// 188.520 us; speedup vs baseline: 1.0798x; 1.0798x over previous
//
#include <hip/hip_runtime.h>

// YOLO-v1 loss forward, S=7, B=2, C=20, bs=16384.
// R12 = R11 with compile fix: __builtin_nontemporal_load needs a NATIVE clang
// vector pointer (ext_vector_type), not HIP_vector_type<float,4>.
//   NT dwordx4 — bytes-per-transaction probe of the ~3.3 TB/s read wall.
//   R10: L3-served vs HBM-direct identical -> limiter is the common
//   CU<->fabric transaction path. If transaction-RATE limited, 16B/lane
//   doubles delivered bytes at the same rate (fill proves 6.8 TB/s transport).
//   Spill-free by construction: single-wave blocks, strict live-range phasing,
//   launch_bounds(64,1). Validity check: WRITE_SIZE must stay ~KB.

#define SS 7
#define CELL_STRIDE 30                         // 5*B + C floats per cell
#define TILE_CELLS 128                         // per wave-private tile
#define TILE_FLOATS (TILE_CELLS * CELL_STRIDE) // 3840 floats = 15360 B
#define NBLOCKS 1280                           // 5 single-wave blocks/CU (30.7 KB LDS)

typedef float vfloat4 __attribute__((ext_vector_type(4)));

__device__ __forceinline__ void wave_lds_fence() {
    __builtin_amdgcn_fence(__ATOMIC_SEQ_CST, "wavefront");
    __builtin_amdgcn_wave_barrier();
}

__device__ __forceinline__ vfloat4 nt_load_f4(const vfloat4* p) {
    return __builtin_nontemporal_load(p);
}

__device__ __forceinline__ float yolo_cell_loss(const float* pv, const float* lv, int cell) {
    const int rem = cell % (SS * SS);
    const float gx = (float)(rem % SS);   // meshgrid 'xy': x = col
    const float gy = (float)(rem / SS);   // y = row

    const float obj = lv[4];
    const float lx = lv[0], ly = lv[1], lw = lv[2], lh = lv[3];
    const float l_cx = (gx + lx) / 7.0f;
    const float l_cy = (gy + ly) / 7.0f;
    const float l_minx = l_cx - lw * 0.5f, l_maxx = l_cx + lw * 0.5f;
    const float l_miny = l_cy - lh * 0.5f, l_maxy = l_cy + lh * 0.5f;
    const float area_l = lw * lh;

    float iou[2], box_err[2], conf[2];
    #pragma unroll
    for (int b = 0; b < 2; ++b) {
        const float px = pv[5 * b + 0], py = pv[5 * b + 1];
        const float pw = pv[5 * b + 2], ph = pv[5 * b + 3];
        conf[b] = pv[5 * b + 4];
        const float p_cx = (gx + px) / 7.0f;
        const float p_cy = (gy + py) / 7.0f;
        const float p_minx = p_cx - pw * 0.5f, p_maxx = p_cx + pw * 0.5f;
        const float p_miny = p_cy - ph * 0.5f, p_maxy = p_cy + ph * 0.5f;
        float iw = fminf(p_maxx, l_maxx) - fmaxf(p_minx, l_minx);
        float ih = fminf(p_maxy, l_maxy) - fmaxf(p_miny, l_miny);
        iw = fmaxf(iw, 0.0f); ih = fmaxf(ih, 0.0f);
        const float inter = iw * ih;
        const float uni = pw * ph + area_l - inter + 1e-10f;
        iou[b] = inter / uni;
        const float dx = px - lx, dy = py - ly;
        const float dw = sqrtf(pw) - sqrtf(lw);
        const float dh = sqrtf(ph) - sqrtf(lh);
        box_err[b] = (dx * dx + dy * dy) + (dw * dw + dh * dh);
    }

    // argmax tie-break: first max wins -> box 1 only if strictly greater
    const int r = (iou[1] > iou[0]) ? 1 : 0;
    const float cr = conf[r], cn = conf[1 - r];

    float loss = obj * (5.0f * box_err[r] + (cr - iou[r]) * (cr - iou[r]));
    loss += 0.5f * ((1.0f - obj) * cr * cr + cn * cn);

    float cls = 0.0f;
    #pragma unroll
    for (int k = 10; k < 30; ++k) {
        const float d = pv[k] - lv[k];
        cls += d * d;
    }
    loss += obj * cls;
    return loss;
}

// extract lane's two cells (floats [60*lane, 60*lane+60)) from an LDS tile
__device__ __forceinline__ void extract_two_cells(const vfloat4* sh4, int lane,
                                                  float* a, float* b) {
    #pragma unroll
    for (int j = 0; j < 15; ++j) {
        const vfloat4 v = sh4[15 * lane + j];
        #pragma unroll
        for (int c = 0; c < 4; ++c) {
            const int f = 4 * j + c;             // compile-time
            if (f < 30) a[f] = v[c];
            else        b[f - 30] = v[c];
        }
    }
}

__global__ __launch_bounds__(64, 1) void yolo_loss_partial(
    const float* __restrict__ preds,
    const float* __restrict__ labels,
    float* __restrict__ partial,
    int ntiles, float inv_bs, int use_atomic)
{
    __shared__ float shP[TILE_FLOATS];       // preds tile  (15360 B)
    __shared__ float shL[TILE_FLOATS];       // labels tile (15360 B)
    vfloat4* shP4 = reinterpret_cast<vfloat4*>(shP);
    vfloat4* shL4 = reinterpret_cast<vfloat4*>(shL);
    const int lane = threadIdx.x;            // 0..63, single-wave block

    float acc = 0.0f;

    for (int tile = blockIdx.x; tile < ntiles; tile += NBLOCKS) {
        const size_t fbase = (size_t)tile * TILE_FLOATS;
        const vfloat4* gp = reinterpret_cast<const vfloat4*>(preds  + fbase);
        const vfloat4* gl = reinterpret_cast<const vfloat4*>(labels + fbase);

        // ---- phase 1: 30 NT dwordx4 loads (30.7 KB in flight) ----
        vfloat4 t[15], u[15];
        #pragma unroll
        for (int k = 0; k < 15; ++k) t[k] = nt_load_f4(gp + lane + 64 * k);
        #pragma unroll
        for (int k = 0; k < 15; ++k) u[k] = nt_load_f4(gl + lane + 64 * k);

        // ---- phase 2: both tiles -> LDS; t,u die here (no spill) ----
        #pragma unroll
        for (int k = 0; k < 15; ++k) shP4[lane + 64 * k] = t[k];
        #pragma unroll
        for (int k = 0; k < 15; ++k) shL4[lane + 64 * k] = u[k];
        wave_lds_fence();                    // writes before cross-lane reads

        // ---- phase 3: extract my two cells from each tile ----
        float pva[CELL_STRIDE], pvb[CELL_STRIDE];
        float lva[CELL_STRIDE], lvb[CELL_STRIDE];
        extract_two_cells(shP4, lane, pva, pvb);
        extract_two_cells(shL4, lane, lva, lvb);
        wave_lds_fence();                    // reads done before next tile

        const int cellA = tile * TILE_CELLS + 2 * lane;
        acc += yolo_cell_loss(pva, lva, cellA);
        acc += yolo_cell_loss(pvb, lvb, cellA + 1);
    }

    acc *= inv_bs;

    // single-wave shuffle reduction
    #pragma unroll
    for (int off = 32; off > 0; off >>= 1)
        acc += __shfl_down(acc, off, 64);

    if (lane == 0) {
        if (use_atomic) atomicAdd(partial, acc);     // fallback: partial==out
        else            partial[blockIdx.x] = acc;
    }
}

__global__ __launch_bounds__(256) void yolo_reduce(
    const float* __restrict__ partial, float* __restrict__ out, int n)
{
    float acc = 0.0f;
    for (int i = threadIdx.x; i < n; i += 256) acc += partial[i];
    #pragma unroll
    for (int off = 32; off > 0; off >>= 1)
        acc += __shfl_down(acc, off, 64);
    __shared__ float wsum[4];
    const int lane = threadIdx.x & 63;
    const int wid  = threadIdx.x >> 6;
    if (lane == 0) wsum[wid] = acc;
    __syncthreads();
    if (threadIdx.x == 0) out[0] = wsum[0] + wsum[1] + wsum[2] + wsum[3];
}

__global__ void yolo_zero_out(float* out) {
    if (threadIdx.x == 0) out[0] = 0.0f;
}

extern "C" void kernel_launch(void* const* d_in, const int* in_sizes, int n_in,
                              void* d_out, int out_size, void* d_ws, size_t ws_size,
                              hipStream_t stream) {
    const float* preds  = (const float*)d_in[0];
    const float* labels = (const float*)d_in[1];
    float* out = (float*)d_out;

    const int ncells = in_sizes[0] / CELL_STRIDE;        // 802816 (divisible by 128)
    const int ntiles = ncells / TILE_CELLS;              // 6272
    const int bs     = ncells / (SS * SS);               // 16384
    const float inv_bs = 1.0f / (float)bs;

    if (ws_size >= NBLOCKS * sizeof(float)) {
        float* partial = (float*)d_ws;
        yolo_loss_partial<<<NBLOCKS, 64, 0, stream>>>(preds, labels, partial,
                                                      ntiles, inv_bs, 0);
        yolo_reduce<<<1, 256, 0, stream>>>(partial, out, NBLOCKS);
    } else {
        yolo_zero_out<<<1, 64, 0, stream>>>(out);
        yolo_loss_partial<<<NBLOCKS, 64, 0, stream>>>(preds, labels, out,
                                                      ntiles, inv_bs, 1);
    }
}